// Round 12
// baseline (1174.285 us; speedup 1.0000x reference)
//
#include <hip/hip_runtime.h>
#include <hip/hip_bf16.h>

#define BATCH 512
#define NNODE 131072
#define NEDGE 131072
#define NLAYER 4
#define SCAN_BLK 1024
#define SCAN_NBLK (NNODE / SCAN_BLK)   // 128
#define PCAP (8 * NEDGE)               // per-pair entry capacity (expected ~4N)
#define NGRP (NNODE / 16)              // 8192 groups for the last sweep

// Per-layer CSR (application order: layer 0 = edges3 ... layer 3 = edges0)
__device__ int g_counts[NLAYER][NNODE];
__device__ int g_offs[NLAYER][NNODE];
__device__ int g_cursor[NLAYER][NNODE];
__device__ int g_srcl[NLAYER][NEDGE];
__device__ int g_bsums[NLAYER][SCAN_NBLK];

// Pair-combined CSR: pair0 = (I+A3)(I+A2), pair1 = (I+A1)(I+A0). Identity included.
__device__ int p_cnt[2][NNODE];
__device__ int p_offs[2][NNODE];
__device__ int p_srcl[2][PCAP];
__device__ int p_bsums[2][SCAN_NBLK];

// Degree-sort scratch
__device__ int s_hist0[64], s_off0[64], s_cur0[64];
__device__ int d_perm0[NNODE];         // pair0 nodes, degree-descending
__device__ int g_sum1[NGRP];
__device__ int s_hist1[256], s_off1[256], s_cur1[256];
__device__ int d_gord1[NGRP];          // pair1 groups, sum-degree-descending

typedef unsigned int uivec4 __attribute__((ext_vector_type(4)));

__device__ __forceinline__ void nt_store_u4(uint4* p, uint4 v) {
    uivec4 w = {v.x, v.y, v.z, v.w};
    __builtin_nontemporal_store(w, reinterpret_cast<uivec4*>(p));
}

// ---- per-layer CSR build ----
__global__ void zero_counts_k() {
    int i = blockIdx.x * blockDim.x + threadIdx.x;
    ((int*)g_counts)[i] = 0;
}

__global__ void hist_k(const int* __restrict__ p0, const int* __restrict__ p1,
                       const int* __restrict__ p2, const int* __restrict__ p3) {
    int i = blockIdx.x * blockDim.x + threadIdx.x;
    int layer = i >> 17;
    int e = i & (NEDGE - 1);
    const int* eg = layer == 0 ? p0 : layer == 1 ? p1 : layer == 2 ? p2 : p3;
    atomicAdd(&g_counts[layer][eg[NEDGE + e]], 1);
}

__global__ void scan_block_k() {
    __shared__ int sh[SCAN_BLK];
    int layer = blockIdx.x / SCAN_NBLK;
    int blk = blockIdx.x % SCAN_NBLK;
    int t = threadIdx.x;
    int i = blk * SCAN_BLK + t;
    int own = g_counts[layer][i];
    sh[t] = own;
    __syncthreads();
    for (int off = 1; off < SCAN_BLK; off <<= 1) {
        int v = (t >= off) ? sh[t - off] : 0;
        __syncthreads();
        sh[t] += v;
        __syncthreads();
    }
    g_offs[layer][i] = sh[t] - own;
    if (t == SCAN_BLK - 1) g_bsums[layer][blk] = sh[t];
}

__global__ void scan_bsums_k() {
    __shared__ int sh[SCAN_NBLK];
    int layer = blockIdx.x;
    int t = threadIdx.x;
    int own = g_bsums[layer][t];
    sh[t] = own;
    __syncthreads();
    for (int off = 1; off < SCAN_NBLK; off <<= 1) {
        int v = (t >= off) ? sh[t - off] : 0;
        __syncthreads();
        sh[t] += v;
        __syncthreads();
    }
    g_bsums[layer][t] = sh[t] - own;
}

__global__ void scan_add_k() {
    int layer = blockIdx.x / SCAN_NBLK;
    int blk = blockIdx.x % SCAN_NBLK;
    int i = blk * SCAN_BLK + threadIdx.x;
    int o = g_offs[layer][i] + g_bsums[layer][blk];
    g_offs[layer][i] = o;
    g_cursor[layer][i] = o;
}

__global__ void fill_k(const int* __restrict__ p0, const int* __restrict__ p1,
                       const int* __restrict__ p2, const int* __restrict__ p3) {
    int i = blockIdx.x * blockDim.x + threadIdx.x;
    int layer = i >> 17;
    int e = i & (NEDGE - 1);
    const int* eg = layer == 0 ? p0 : layer == 1 ? p1 : layer == 2 ? p2 : p3;
    int s = eg[e];
    int d = eg[NEDGE + e];
    int p = atomicAdd(&g_cursor[layer][d], 1);
    g_srcl[layer][p] = s;
}

// ---- pair combine ----
__global__ void count_pair_k() {
    int i = blockIdx.x * blockDim.x + threadIdx.x;  // 0..2N
    int pr = i >> 17;
    int d = i & (NNODE - 1);
    int U = pr * 2, V = pr * 2 + 1;
    int c = 1 + g_counts[U][d];
    int vb = g_offs[V][d], vd = g_counts[V][d];
    for (int j = 0; j < vd; ++j) {
        int s = g_srcl[V][vb + j];
        c += 1 + g_counts[U][s];
    }
    p_cnt[pr][d] = c;
}

__global__ void pscan_block_k() {
    __shared__ int sh[SCAN_BLK];
    int pr = blockIdx.x / SCAN_NBLK;
    int blk = blockIdx.x % SCAN_NBLK;
    int t = threadIdx.x;
    int i = blk * SCAN_BLK + t;
    int own = p_cnt[pr][i];
    sh[t] = own;
    __syncthreads();
    for (int off = 1; off < SCAN_BLK; off <<= 1) {
        int v = (t >= off) ? sh[t - off] : 0;
        __syncthreads();
        sh[t] += v;
        __syncthreads();
    }
    p_offs[pr][i] = sh[t] - own;
    if (t == SCAN_BLK - 1) p_bsums[pr][blk] = sh[t];
}

__global__ void pscan_bsums_k() {
    __shared__ int sh[SCAN_NBLK];
    int pr = blockIdx.x;
    int t = threadIdx.x;
    int own = p_bsums[pr][t];
    sh[t] = own;
    __syncthreads();
    for (int off = 1; off < SCAN_NBLK; off <<= 1) {
        int v = (t >= off) ? sh[t - off] : 0;
        __syncthreads();
        sh[t] += v;
        __syncthreads();
    }
    p_bsums[pr][t] = sh[t] - own;
}

__global__ void pscan_add_k() {
    int pr = blockIdx.x / SCAN_NBLK;
    int blk = blockIdx.x % SCAN_NBLK;
    int i = blk * SCAN_BLK + threadIdx.x;
    p_offs[pr][i] += p_bsums[pr][blk];
}

__global__ void fill_pair_k() {
    int i = blockIdx.x * blockDim.x + threadIdx.x;  // 0..2N
    int pr = i >> 17;
    int d = i & (NNODE - 1);
    int U = pr * 2, V = pr * 2 + 1;
    int p = p_offs[pr][d];
    int* buf = p_srcl[pr];
    buf[p++] = d;
    int ub = g_offs[U][d], ud = g_counts[U][d];
    for (int j = 0; j < ud; ++j) buf[p++] = g_srcl[U][ub + j];
    int vb = g_offs[V][d], vd = g_counts[V][d];
    for (int j = 0; j < vd; ++j) {
        int s = g_srcl[V][vb + j];
        buf[p++] = s;
        int sb = g_offs[U][s], sd = g_counts[U][s];
        for (int k = 0; k < sd; ++k) buf[p++] = g_srcl[U][sb + k];
    }
}

// ---- degree-sort build ----
__global__ void sort_zero_k() {
    int t = threadIdx.x;
    if (t < 64) { s_hist0[t] = 0; }
    s_hist1[t] = 0;
}

__global__ void hist0_k() {   // 128 blocks x 1024
    __shared__ int lh[64];
    int t = threadIdx.x;
    if (t < 64) lh[t] = 0;
    __syncthreads();
    int n = blockIdx.x * 1024 + t;
    int b = 63 - min(p_cnt[0][n], 63);   // descending: heavy first
    atomicAdd(&lh[b], 1);
    __syncthreads();
    if (t < 64) atomicAdd(&s_hist0[t], lh[t]);
}

__global__ void gsum1_k() {   // 8 blocks x 1024
    int g = blockIdx.x * blockDim.x + threadIdx.x;
    int s = 0;
#pragma unroll
    for (int k = 0; k < 16; ++k) s += p_cnt[1][g * 16 + k];
    g_sum1[g] = s;
}

__global__ void hist1_k() {   // 8 blocks x 1024
    __shared__ int lh[256];
    int t = threadIdx.x;
    if (t < 256) lh[t] = 0;
    __syncthreads();
    int g = blockIdx.x * 1024 + t;
    int b = 255 - min(g_sum1[g], 255);
    atomicAdd(&lh[b], 1);
    __syncthreads();
    if (t < 256) atomicAdd(&s_hist1[t], lh[t]);
}

__global__ void sort_scan_k() {
    int t = threadIdx.x;
    if (t == 0) {
        int a = 0;
        for (int k = 0; k < 64; ++k) { int v = s_hist0[k]; s_off0[k] = a; s_cur0[k] = a; a += v; }
    }
    if (t == 1) {
        int a = 0;
        for (int k = 0; k < 256; ++k) { int v = s_hist1[k]; s_off1[k] = a; s_cur1[k] = a; a += v; }
    }
}

__global__ void perm0_k() {   // 128 blocks x 1024
    __shared__ int lh[64];
    __shared__ int lbase[64];
    int t = threadIdx.x;
    if (t < 64) lh[t] = 0;
    __syncthreads();
    int n = blockIdx.x * 1024 + t;
    int b = 63 - min(p_cnt[0][n], 63);
    int lpos = atomicAdd(&lh[b], 1);
    __syncthreads();
    if (t < 64) lbase[t] = lh[t] ? atomicAdd(&s_cur0[t], lh[t]) : 0;
    __syncthreads();
    d_perm0[lbase[b] + lpos] = n;
}

__global__ void gord1_k() {   // 8 blocks x 1024
    __shared__ int lh[256];
    __shared__ int lbase[256];
    int t = threadIdx.x;
    if (t < 256) lh[t] = 0;
    __syncthreads();
    int g = blockIdx.x * 1024 + t;
    int b = 255 - min(g_sum1[g], 255);
    int lpos = atomicAdd(&lh[b], 1);
    __syncthreads();
    if (t < 256) lbase[t] = lh[t] ? atomicAdd(&s_cur1[t], lh[t]) : 0;
    __syncthreads();
    d_gord1[lbase[b] + lpos] = g;
}

// ---- transpose with bf16 output: x (B,N) f32 -> out (N,B) bf16 ----
__global__ void transpose_bf_k(const float* __restrict__ in, unsigned short* __restrict__ out) {
    __shared__ float tile[64][65];
    int c0 = blockIdx.x * 64;   // N dim
    int r0 = blockIdx.y * 64;   // B dim
    int tx = threadIdx.x;
    int ty = threadIdx.y;
    float4 v[4];
#pragma unroll
    for (int i = 0; i < 4; ++i)
        v[i] = *reinterpret_cast<const float4*>(&in[(size_t)(r0 + ty + 16 * i) * NNODE + c0 + 4 * tx]);
#pragma unroll
    for (int i = 0; i < 4; ++i) {
        tile[ty + 16 * i][4 * tx + 0] = v[i].x;
        tile[ty + 16 * i][4 * tx + 1] = v[i].y;
        tile[ty + 16 * i][4 * tx + 2] = v[i].z;
        tile[ty + 16 * i][4 * tx + 3] = v[i].w;
    }
    __syncthreads();
#pragma unroll
    for (int i = 0; i < 4; ++i) {
        int n = c0 + ty + 16 * i;
        ushort4 w;
        __hip_bfloat16 h0 = __float2bfloat16(tile[4 * tx + 0][ty + 16 * i]);
        __hip_bfloat16 h1 = __float2bfloat16(tile[4 * tx + 1][ty + 16 * i]);
        __hip_bfloat16 h2 = __float2bfloat16(tile[4 * tx + 2][ty + 16 * i]);
        __hip_bfloat16 h3 = __float2bfloat16(tile[4 * tx + 3][ty + 16 * i]);
        w.x = *reinterpret_cast<unsigned short*>(&h0);
        w.y = *reinterpret_cast<unsigned short*>(&h1);
        w.z = *reinterpret_cast<unsigned short*>(&h2);
        w.w = *reinterpret_cast<unsigned short*>(&h3);
        *reinterpret_cast<ushort4*>(&out[(size_t)n * BATCH + r0 + 4 * tx]) = w;
    }
}

// bf16 unpack-accumulate: uint4 = 8 bf16 -> 8 f32 adds
__device__ __forceinline__ void gacc8(float* a, uint4 v) {
    a[0] += __uint_as_float(v.x << 16);
    a[1] += __uint_as_float(v.x & 0xffff0000u);
    a[2] += __uint_as_float(v.y << 16);
    a[3] += __uint_as_float(v.y & 0xffff0000u);
    a[4] += __uint_as_float(v.z << 16);
    a[5] += __uint_as_float(v.z & 0xffff0000u);
    a[6] += __uint_as_float(v.w << 16);
    a[7] += __uint_as_float(v.w & 0xffff0000u);
}

__device__ __forceinline__ unsigned pack2(float lo, float hi) {
    __hip_bfloat16 l = __float2bfloat16(lo);
    __hip_bfloat16 h = __float2bfloat16(hi);
    return (unsigned)*reinterpret_cast<unsigned short*>(&l) |
           ((unsigned)*reinterpret_cast<unsigned short*>(&h) << 16);
}

// Shared gather body: cur (N,B) bf16 as uint4 (64/node). x4 unroll, 4 acc sets.
__device__ __forceinline__ void gather_body_bf(const uint4* __restrict__ cur,
                                               const int* __restrict__ sl, int deg, int q,
                                               float acc[8]) {
    float A[8] = {0, 0, 0, 0, 0, 0, 0, 0};
    float B_[8] = {0, 0, 0, 0, 0, 0, 0, 0};
    float C_[8] = {0, 0, 0, 0, 0, 0, 0, 0};
    float D_[8] = {0, 0, 0, 0, 0, 0, 0, 0};
    int j = 0;
    for (; j + 4 <= deg; j += 4) {
        uint4 v0 = cur[(size_t)sl[j + 0] * 64 + q];
        uint4 v1 = cur[(size_t)sl[j + 1] * 64 + q];
        uint4 v2 = cur[(size_t)sl[j + 2] * 64 + q];
        uint4 v3 = cur[(size_t)sl[j + 3] * 64 + q];
        gacc8(A, v0);
        gacc8(B_, v1);
        gacc8(C_, v2);
        gacc8(D_, v3);
    }
    for (; j < deg; ++j) {
        uint4 v = cur[(size_t)sl[j] * 64 + q];
        gacc8(A, v);
    }
#pragma unroll
    for (int k = 0; k < 8; ++k) acc[k] = A[k] + B_[k] + C_[k] + D_[k];
}

// ---- pair gather (bf16 -> bf16): 8 degree-sorted nodes per 512-thread block ----
__global__ void gather_p_k(const uint4* __restrict__ cur, uint4* __restrict__ out,
                           int pr) {
    int t = threadIdx.x;
    int n = d_perm0[blockIdx.x * 8 + (t >> 6)];
    int q = t & 63;
    int beg = p_offs[pr][n];
    int deg = p_cnt[pr][n];
    float acc[8];
    gather_body_bf(cur, &p_srcl[pr][beg], deg, q, acc);
    uint4 w;
    w.x = pack2(acc[0], acc[1]);
    w.y = pack2(acc[2], acc[3]);
    w.z = pack2(acc[4], acc[5]);
    w.w = pack2(acc[6], acc[7]);
    nt_store_u4(&out[(size_t)n * 64 + q], w);
}

// ---- last pair gather fused with transpose-back, barrier-free:
// ONE WAVE per 16-node group (LPT-ordered). Lane q accumulates b=8q..8q+7 for
// all 16 nodes (acc[16][8], fully unrolled), then writes rows b=8q..8q+7:
// 64 B contiguous per lane per row (cached stores; L2 assembles lines).
__global__ void __launch_bounds__(512) gather_tr_w_k(const uint4* __restrict__ cur,
                                                     float* __restrict__ out, int pr) {
    int t = threadIdx.x;
    int wid = blockIdx.x * 8 + (t >> 6);
    int g = d_gord1[wid];
    int n0 = g * 16;
    int q = t & 63;
    float acc[16][8];
#pragma unroll
    for (int k = 0; k < 16; ++k) {
        int n = n0 + k;
        int beg = p_offs[pr][n];
        int deg = p_cnt[pr][n];
        gather_body_bf(cur, &p_srcl[pr][beg], deg, q, acc[k]);
    }
#pragma unroll
    for (int r = 0; r < 8; ++r) {
        int b = 8 * q + r;
        float4* orow = reinterpret_cast<float4*>(&out[(size_t)b * NNODE + n0]);
        orow[0] = make_float4(acc[0][r], acc[1][r], acc[2][r], acc[3][r]);
        orow[1] = make_float4(acc[4][r], acc[5][r], acc[6][r], acc[7][r]);
        orow[2] = make_float4(acc[8][r], acc[9][r], acc[10][r], acc[11][r]);
        orow[3] = make_float4(acc[12][r], acc[13][r], acc[14][r], acc[15][r]);
    }
}

extern "C" void kernel_launch(void* const* d_in, const int* in_sizes, int n_in,
                              void* d_out, int out_size, void* d_ws, size_t ws_size,
                              hipStream_t stream) {
    const float* x = (const float*)d_in[0];
    // Application order: edges3 (layer 0) ... edges0 (layer 3)
    const int* p0 = (const int*)d_in[4];
    const int* p1 = (const int*)d_in[3];
    const int* p2 = (const int*)d_in[2];
    const int* p3 = (const int*)d_in[1];

    // Two bf16 (N,B) buffers in d_ws: 128 MB each
    unsigned short* WS0 = (unsigned short*)d_ws;
    unsigned short* WS1 = WS0 + (size_t)NNODE * BATCH;
    float* OUT = (float*)d_out;

    // Per-layer CSR
    zero_counts_k<<<NLAYER * NNODE / 1024, 1024, 0, stream>>>();
    hist_k<<<NLAYER * NEDGE / 1024, 1024, 0, stream>>>(p0, p1, p2, p3);
    scan_block_k<<<NLAYER * SCAN_NBLK, SCAN_BLK, 0, stream>>>();
    scan_bsums_k<<<NLAYER, SCAN_NBLK, 0, stream>>>();
    scan_add_k<<<NLAYER * SCAN_NBLK, SCAN_BLK, 0, stream>>>();
    fill_k<<<NLAYER * NEDGE / 1024, 1024, 0, stream>>>(p0, p1, p2, p3);

    // Pair-combined CSR (2 pairs)
    count_pair_k<<<2 * NNODE / 1024, 1024, 0, stream>>>();
    pscan_block_k<<<2 * SCAN_NBLK, SCAN_BLK, 0, stream>>>();
    pscan_bsums_k<<<2, SCAN_NBLK, 0, stream>>>();
    pscan_add_k<<<2 * SCAN_NBLK, SCAN_BLK, 0, stream>>>();
    fill_pair_k<<<2 * NNODE / 256, 256, 0, stream>>>();

    // Degree-sort (uses p_cnt only; independent of fill_pair)
    sort_zero_k<<<1, 256, 0, stream>>>();
    hist0_k<<<NNODE / 1024, 1024, 0, stream>>>();
    gsum1_k<<<NGRP / 1024, 1024, 0, stream>>>();
    hist1_k<<<NGRP / 1024, 1024, 0, stream>>>();
    sort_scan_k<<<1, 64, 0, stream>>>();
    perm0_k<<<NNODE / 1024, 1024, 0, stream>>>();
    gord1_k<<<NGRP / 1024, 1024, 0, stream>>>();

    // x (B,N) f32 -> WS0 (N,B) bf16
    transpose_bf_k<<<dim3(NNODE / 64, BATCH / 64), dim3(16, 16), 0, stream>>>(x, WS0);

    // sweep 0 (pair 0): WS0 -> WS1 (bf16, full-line NT), degree-sorted
    gather_p_k<<<NNODE / 8, 512, 0, stream>>>((const uint4*)WS0, (uint4*)WS1, 0);
    // sweep 1 (pair 1): barrier-free wave-per-group, LPT order, fused transpose-back
    gather_tr_w_k<<<NGRP / 8, 512, 0, stream>>>((const uint4*)WS1, OUT, 1);
}

// Round 13
// 533.401 us; speedup vs baseline: 2.2015x; 2.2015x over previous
//
#include <hip/hip_runtime.h>
#include <hip/hip_bf16.h>

#define BATCH 512
#define NNODE 131072
#define NEDGE 131072
#define NLAYER 4
#define SCAN_BLK 1024
#define SCAN_NBLK (NNODE / SCAN_BLK)   // 128
#define PCAP (8 * NEDGE)               // per-pair entry capacity (expected ~4N)
#define NGRP (NNODE / 16)              // 8192 groups for the last sweep

// Per-layer CSR (application order: layer 0 = edges3 ... layer 3 = edges0)
__device__ int g_counts[NLAYER][NNODE];
__device__ int g_offs[NLAYER][NNODE];
__device__ int g_cursor[NLAYER][NNODE];
__device__ int g_srcl[NLAYER][NEDGE];
__device__ int g_bsums[NLAYER][SCAN_NBLK];

// Pair-combined CSR: pair0 = (I+A3)(I+A2), pair1 = (I+A1)(I+A0). Identity included.
__device__ int p_cnt[2][NNODE];
__device__ int p_offs[2][NNODE];
__device__ int p_srcl[2][PCAP];
__device__ int p_bsums[2][SCAN_NBLK];

// LPT-order scratch
__device__ int s_hist0[64], s_cur0[64];
__device__ int d_perm0[NNODE];         // pair0 nodes, degree-descending
__device__ int g_sum1[NGRP];
__device__ int s_hist1[256], s_cur1[256];
__device__ int d_gord1[NGRP];          // pair1 groups, sum-degree-descending

typedef unsigned int uivec4 __attribute__((ext_vector_type(4)));
typedef float fvec4 __attribute__((ext_vector_type(4)));

__device__ __forceinline__ void nt_store_u4(uint4* p, uint4 v) {
    uivec4 w = {v.x, v.y, v.z, v.w};
    __builtin_nontemporal_store(w, reinterpret_cast<uivec4*>(p));
}

__device__ __forceinline__ void nt_store_f4(float* p, float4 v) {
    fvec4 w = {v.x, v.y, v.z, v.w};
    __builtin_nontemporal_store(w, reinterpret_cast<fvec4*>(p));
}

// ---- per-layer CSR build ----
__global__ void zero_counts_k() {
    int i = blockIdx.x * blockDim.x + threadIdx.x;
    ((int*)g_counts)[i] = 0;
}

__global__ void hist_k(const int* __restrict__ p0, const int* __restrict__ p1,
                       const int* __restrict__ p2, const int* __restrict__ p3) {
    int i = blockIdx.x * blockDim.x + threadIdx.x;
    int layer = i >> 17;
    int e = i & (NEDGE - 1);
    const int* eg = layer == 0 ? p0 : layer == 1 ? p1 : layer == 2 ? p2 : p3;
    atomicAdd(&g_counts[layer][eg[NEDGE + e]], 1);
}

__global__ void scan_block_k() {
    __shared__ int sh[SCAN_BLK];
    int layer = blockIdx.x / SCAN_NBLK;
    int blk = blockIdx.x % SCAN_NBLK;
    int t = threadIdx.x;
    int i = blk * SCAN_BLK + t;
    int own = g_counts[layer][i];
    sh[t] = own;
    __syncthreads();
    for (int off = 1; off < SCAN_BLK; off <<= 1) {
        int v = (t >= off) ? sh[t - off] : 0;
        __syncthreads();
        sh[t] += v;
        __syncthreads();
    }
    g_offs[layer][i] = sh[t] - own;
    if (t == SCAN_BLK - 1) g_bsums[layer][blk] = sh[t];
}

__global__ void scan_bsums_k() {
    __shared__ int sh[SCAN_NBLK];
    int layer = blockIdx.x;
    int t = threadIdx.x;
    int own = g_bsums[layer][t];
    sh[t] = own;
    __syncthreads();
    for (int off = 1; off < SCAN_NBLK; off <<= 1) {
        int v = (t >= off) ? sh[t - off] : 0;
        __syncthreads();
        sh[t] += v;
        __syncthreads();
    }
    g_bsums[layer][t] = sh[t] - own;
}

__global__ void scan_add_k() {
    int layer = blockIdx.x / SCAN_NBLK;
    int blk = blockIdx.x % SCAN_NBLK;
    int i = blk * SCAN_BLK + threadIdx.x;
    int o = g_offs[layer][i] + g_bsums[layer][blk];
    g_offs[layer][i] = o;
    g_cursor[layer][i] = o;
}

__global__ void fill_k(const int* __restrict__ p0, const int* __restrict__ p1,
                       const int* __restrict__ p2, const int* __restrict__ p3) {
    int i = blockIdx.x * blockDim.x + threadIdx.x;
    int layer = i >> 17;
    int e = i & (NEDGE - 1);
    const int* eg = layer == 0 ? p0 : layer == 1 ? p1 : layer == 2 ? p2 : p3;
    int s = eg[e];
    int d = eg[NEDGE + e];
    int p = atomicAdd(&g_cursor[layer][d], 1);
    g_srcl[layer][p] = s;
}

// ---- pair combine ----
__global__ void count_pair_k() {
    int i = blockIdx.x * blockDim.x + threadIdx.x;  // 0..2N
    int pr = i >> 17;
    int d = i & (NNODE - 1);
    int U = pr * 2, V = pr * 2 + 1;
    int c = 1 + g_counts[U][d];
    int vb = g_offs[V][d], vd = g_counts[V][d];
    for (int j = 0; j < vd; ++j) {
        int s = g_srcl[V][vb + j];
        c += 1 + g_counts[U][s];
    }
    p_cnt[pr][d] = c;
}

__global__ void pscan_block_k() {
    __shared__ int sh[SCAN_BLK];
    int pr = blockIdx.x / SCAN_NBLK;
    int blk = blockIdx.x % SCAN_NBLK;
    int t = threadIdx.x;
    int i = blk * SCAN_BLK + t;
    int own = p_cnt[pr][i];
    sh[t] = own;
    __syncthreads();
    for (int off = 1; off < SCAN_BLK; off <<= 1) {
        int v = (t >= off) ? sh[t - off] : 0;
        __syncthreads();
        sh[t] += v;
        __syncthreads();
    }
    p_offs[pr][i] = sh[t] - own;
    if (t == SCAN_BLK - 1) p_bsums[pr][blk] = sh[t];
}

__global__ void pscan_bsums_k() {
    __shared__ int sh[SCAN_NBLK];
    int pr = blockIdx.x;
    int t = threadIdx.x;
    int own = p_bsums[pr][t];
    sh[t] = own;
    __syncthreads();
    for (int off = 1; off < SCAN_NBLK; off <<= 1) {
        int v = (t >= off) ? sh[t - off] : 0;
        __syncthreads();
        sh[t] += v;
        __syncthreads();
    }
    p_bsums[pr][t] = sh[t] - own;
}

__global__ void pscan_add_k() {
    int pr = blockIdx.x / SCAN_NBLK;
    int blk = blockIdx.x % SCAN_NBLK;
    int i = blk * SCAN_BLK + threadIdx.x;
    p_offs[pr][i] += p_bsums[pr][blk];
}

__global__ void fill_pair_k() {
    int i = blockIdx.x * blockDim.x + threadIdx.x;  // 0..2N
    int pr = i >> 17;
    int d = i & (NNODE - 1);
    int U = pr * 2, V = pr * 2 + 1;
    int p = p_offs[pr][d];
    int* buf = p_srcl[pr];
    buf[p++] = d;
    int ub = g_offs[U][d], ud = g_counts[U][d];
    for (int j = 0; j < ud; ++j) buf[p++] = g_srcl[U][ub + j];
    int vb = g_offs[V][d], vd = g_counts[V][d];
    for (int j = 0; j < vd; ++j) {
        int s = g_srcl[V][vb + j];
        buf[p++] = s;
        int sb = g_offs[U][s], sd = g_counts[U][s];
        for (int k = 0; k < sd; ++k) buf[p++] = g_srcl[U][sb + k];
    }
}

// ---- LPT ordering build ----
__global__ void sort_zero_k() {
    int t = threadIdx.x;
    if (t < 64) s_hist0[t] = 0;
    s_hist1[t] = 0;
}

__global__ void hist0_k() {   // 128 blocks x 1024
    __shared__ int lh[64];
    int t = threadIdx.x;
    if (t < 64) lh[t] = 0;
    __syncthreads();
    int n = blockIdx.x * 1024 + t;
    int b = 63 - min(p_cnt[0][n], 63);   // descending: heavy first
    atomicAdd(&lh[b], 1);
    __syncthreads();
    if (t < 64) atomicAdd(&s_hist0[t], lh[t]);
}

__global__ void gsum1_k() {   // 8 blocks x 1024
    int g = blockIdx.x * blockDim.x + threadIdx.x;
    int s = 0;
#pragma unroll
    for (int k = 0; k < 16; ++k) s += p_cnt[1][g * 16 + k];
    g_sum1[g] = s;
}

__global__ void hist1_k() {   // 8 blocks x 1024
    __shared__ int lh[256];
    int t = threadIdx.x;
    if (t < 256) lh[t] = 0;
    __syncthreads();
    int g = blockIdx.x * 1024 + t;
    int b = 255 - min(g_sum1[g], 255);
    atomicAdd(&lh[b], 1);
    __syncthreads();
    if (t < 256) atomicAdd(&s_hist1[t], lh[t]);
}

// parallel exclusive scans of the two small histograms (1 block, 256 threads)
__global__ void sort_scan_k() {
    __shared__ int sh0[64];
    __shared__ int sh1[256];
    int t = threadIdx.x;
    if (t < 64) sh0[t] = s_hist0[t];
    sh1[t] = s_hist1[t];
    __syncthreads();
    for (int off = 1; off < 64; off <<= 1) {
        int v = (t < 64 && t >= off) ? sh0[t - off] : 0;
        __syncthreads();
        if (t < 64) sh0[t] += v;
        __syncthreads();
    }
    for (int off = 1; off < 256; off <<= 1) {
        int v = (t >= off) ? sh1[t - off] : 0;
        __syncthreads();
        sh1[t] += v;
        __syncthreads();
    }
    if (t < 64) s_cur0[t] = sh0[t] - s_hist0[t];
    s_cur1[t] = sh1[t] - s_hist1[t];
}

__global__ void perm0_k() {   // 128 blocks x 1024
    __shared__ int lh[64];
    __shared__ int lbase[64];
    int t = threadIdx.x;
    if (t < 64) lh[t] = 0;
    __syncthreads();
    int n = blockIdx.x * 1024 + t;
    int b = 63 - min(p_cnt[0][n], 63);
    int lpos = atomicAdd(&lh[b], 1);
    __syncthreads();
    if (t < 64) lbase[t] = lh[t] ? atomicAdd(&s_cur0[t], lh[t]) : 0;
    __syncthreads();
    d_perm0[lbase[b] + lpos] = n;
}

__global__ void gord1_k() {   // 8 blocks x 1024
    __shared__ int lh[256];
    __shared__ int lbase[256];
    int t = threadIdx.x;
    if (t < 256) lh[t] = 0;
    __syncthreads();
    int g = blockIdx.x * 1024 + t;
    int b = 255 - min(g_sum1[g], 255);
    int lpos = atomicAdd(&lh[b], 1);
    __syncthreads();
    if (t < 256) lbase[t] = lh[t] ? atomicAdd(&s_cur1[t], lh[t]) : 0;
    __syncthreads();
    d_gord1[lbase[b] + lpos] = g;
}

// ---- transpose with bf16 output: x (B,N) f32 -> out (N,B) bf16 ----
__global__ void transpose_bf_k(const float* __restrict__ in, unsigned short* __restrict__ out) {
    __shared__ float tile[64][65];
    int c0 = blockIdx.x * 64;   // N dim
    int r0 = blockIdx.y * 64;   // B dim
    int tx = threadIdx.x;
    int ty = threadIdx.y;
    float4 v[4];
#pragma unroll
    for (int i = 0; i < 4; ++i)
        v[i] = *reinterpret_cast<const float4*>(&in[(size_t)(r0 + ty + 16 * i) * NNODE + c0 + 4 * tx]);
#pragma unroll
    for (int i = 0; i < 4; ++i) {
        tile[ty + 16 * i][4 * tx + 0] = v[i].x;
        tile[ty + 16 * i][4 * tx + 1] = v[i].y;
        tile[ty + 16 * i][4 * tx + 2] = v[i].z;
        tile[ty + 16 * i][4 * tx + 3] = v[i].w;
    }
    __syncthreads();
#pragma unroll
    for (int i = 0; i < 4; ++i) {
        int n = c0 + ty + 16 * i;
        ushort4 w;
        __hip_bfloat16 h0 = __float2bfloat16(tile[4 * tx + 0][ty + 16 * i]);
        __hip_bfloat16 h1 = __float2bfloat16(tile[4 * tx + 1][ty + 16 * i]);
        __hip_bfloat16 h2 = __float2bfloat16(tile[4 * tx + 2][ty + 16 * i]);
        __hip_bfloat16 h3 = __float2bfloat16(tile[4 * tx + 3][ty + 16 * i]);
        w.x = *reinterpret_cast<unsigned short*>(&h0);
        w.y = *reinterpret_cast<unsigned short*>(&h1);
        w.z = *reinterpret_cast<unsigned short*>(&h2);
        w.w = *reinterpret_cast<unsigned short*>(&h3);
        *reinterpret_cast<ushort4*>(&out[(size_t)n * BATCH + r0 + 4 * tx]) = w;
    }
}

// bf16 unpack-accumulate: uint4 = 8 bf16 -> 8 f32 adds
__device__ __forceinline__ void gacc8(float* a, uint4 v) {
    a[0] += __uint_as_float(v.x << 16);
    a[1] += __uint_as_float(v.x & 0xffff0000u);
    a[2] += __uint_as_float(v.y << 16);
    a[3] += __uint_as_float(v.y & 0xffff0000u);
    a[4] += __uint_as_float(v.z << 16);
    a[5] += __uint_as_float(v.z & 0xffff0000u);
    a[6] += __uint_as_float(v.w << 16);
    a[7] += __uint_as_float(v.w & 0xffff0000u);
}

__device__ __forceinline__ unsigned pack2(float lo, float hi) {
    __hip_bfloat16 l = __float2bfloat16(lo);
    __hip_bfloat16 h = __float2bfloat16(hi);
    return (unsigned)*reinterpret_cast<unsigned short*>(&l) |
           ((unsigned)*reinterpret_cast<unsigned short*>(&h) << 16);
}

// Shared gather body: cur (N,B) bf16 as uint4 (64/node). x4 unroll, 4 acc sets.
__device__ __forceinline__ void gather_body_bf(const uint4* __restrict__ cur,
                                               const int* __restrict__ sl, int deg, int q,
                                               float acc[8]) {
    float A[8] = {0, 0, 0, 0, 0, 0, 0, 0};
    float B_[8] = {0, 0, 0, 0, 0, 0, 0, 0};
    float C_[8] = {0, 0, 0, 0, 0, 0, 0, 0};
    float D_[8] = {0, 0, 0, 0, 0, 0, 0, 0};
    int j = 0;
    for (; j + 4 <= deg; j += 4) {
        uint4 v0 = cur[(size_t)sl[j + 0] * 64 + q];
        uint4 v1 = cur[(size_t)sl[j + 1] * 64 + q];
        uint4 v2 = cur[(size_t)sl[j + 2] * 64 + q];
        uint4 v3 = cur[(size_t)sl[j + 3] * 64 + q];
        gacc8(A, v0);
        gacc8(B_, v1);
        gacc8(C_, v2);
        gacc8(D_, v3);
    }
    for (; j < deg; ++j) {
        uint4 v = cur[(size_t)sl[j] * 64 + q];
        gacc8(A, v);
    }
#pragma unroll
    for (int k = 0; k < 8; ++k) acc[k] = A[k] + B_[k] + C_[k] + D_[k];
}

// ---- pair gather (bf16 -> bf16): 8 LPT-ordered nodes per 512-thread block.
// Full-line NT store (wave writes 1 KB contiguous).
__global__ void gather_p_k(const uint4* __restrict__ cur, uint4* __restrict__ out,
                           int pr) {
    int t = threadIdx.x;
    int n = d_perm0[blockIdx.x * 8 + (t >> 6)];
    int q = t & 63;
    int beg = p_offs[pr][n];
    int deg = p_cnt[pr][n];
    float acc[8];
    gather_body_bf(cur, &p_srcl[pr][beg], deg, q, acc);
    uint4 w;
    w.x = pack2(acc[0], acc[1]);
    w.y = pack2(acc[2], acc[3]);
    w.z = pack2(acc[4], acc[5]);
    w.w = pack2(acc[6], acc[7]);
    nt_store_u4(&out[(size_t)n * 64 + q], w);
}

// ---- last pair gather (bf16 -> f32) fused with transpose-back.
// 1024 threads, 16 nodes/block (one wave per node), blocks in LPT group order.
// LDS layout = R6's conflict-free [16][129] float4 tile:
//   lane q stages b=8q..8q+3 at lds4[nn][q], b=8q+4..8q+7 at lds4[nn][64+q].
// Read remap: float pos p(b) = (b&7)<4 ? 4*(b>>3)+(b&3) : 256+4*(b>>3)+(b&3).
// Write phase: 4 consecutive lanes cover one row's 16 floats = full 64B lines (NT-safe).
__global__ void __launch_bounds__(1024) gather_tr_p_k(const uint4* __restrict__ cur,
                                                      float* __restrict__ out, int pr) {
    __shared__ float4 lds4[16][129];
    int t = threadIdx.x;
    int g = d_gord1[blockIdx.x];
    int n0 = g * 16;
    int nn = t >> 6;            // 0..15 (wave id = node)
    int q = t & 63;
    int n = n0 + nn;
    int beg = p_offs[pr][n];
    int deg = p_cnt[pr][n];
    float acc[8];
    gather_body_bf(cur, &p_srcl[pr][beg], deg, q, acc);
    lds4[nn][q] = make_float4(acc[0], acc[1], acc[2], acc[3]);
    lds4[nn][64 + q] = make_float4(acc[4], acc[5], acc[6], acc[7]);
    __syncthreads();
    const float* f = (const float*)lds4;   // node stride = 516 floats
    int c = t & 3;              // chunk within row (4 nodes)
    int rb = t >> 2;            // 0..255
#pragma unroll
    for (int iter = 0; iter < 2; ++iter) {
        int b = iter * 256 + rb;
        int r = b & 7;
        int p = (r < 4) ? 4 * (b >> 3) + r : 256 + 4 * (b >> 3) + (r - 4);
        float4 w;
        w.x = f[(4 * c + 0) * 516 + p];
        w.y = f[(4 * c + 1) * 516 + p];
        w.z = f[(4 * c + 2) * 516 + p];
        w.w = f[(4 * c + 3) * 516 + p];
        nt_store_f4(&out[(size_t)b * NNODE + n0 + 4 * c], w);
    }
}

extern "C" void kernel_launch(void* const* d_in, const int* in_sizes, int n_in,
                              void* d_out, int out_size, void* d_ws, size_t ws_size,
                              hipStream_t stream) {
    const float* x = (const float*)d_in[0];
    // Application order: edges3 (layer 0) ... edges0 (layer 3)
    const int* p0 = (const int*)d_in[4];
    const int* p1 = (const int*)d_in[3];
    const int* p2 = (const int*)d_in[2];
    const int* p3 = (const int*)d_in[1];

    // Two bf16 (N,B) buffers in d_ws: 128 MB each
    unsigned short* WS0 = (unsigned short*)d_ws;
    unsigned short* WS1 = WS0 + (size_t)NNODE * BATCH;
    float* OUT = (float*)d_out;

    // Per-layer CSR
    zero_counts_k<<<NLAYER * NNODE / 1024, 1024, 0, stream>>>();
    hist_k<<<NLAYER * NEDGE / 1024, 1024, 0, stream>>>(p0, p1, p2, p3);
    scan_block_k<<<NLAYER * SCAN_NBLK, SCAN_BLK, 0, stream>>>();
    scan_bsums_k<<<NLAYER, SCAN_NBLK, 0, stream>>>();
    scan_add_k<<<NLAYER * SCAN_NBLK, SCAN_BLK, 0, stream>>>();
    fill_k<<<NLAYER * NEDGE / 1024, 1024, 0, stream>>>(p0, p1, p2, p3);

    // Pair-combined CSR (2 pairs)
    count_pair_k<<<2 * NNODE / 1024, 1024, 0, stream>>>();
    pscan_block_k<<<2 * SCAN_NBLK, SCAN_BLK, 0, stream>>>();
    pscan_bsums_k<<<2, SCAN_NBLK, 0, stream>>>();
    pscan_add_k<<<2 * SCAN_NBLK, SCAN_BLK, 0, stream>>>();
    fill_pair_k<<<2 * NNODE / 256, 256, 0, stream>>>();

    // LPT ordering (depends only on p_cnt)
    sort_zero_k<<<1, 256, 0, stream>>>();
    hist0_k<<<NNODE / 1024, 1024, 0, stream>>>();
    gsum1_k<<<NGRP / 1024, 1024, 0, stream>>>();
    hist1_k<<<NGRP / 1024, 1024, 0, stream>>>();
    sort_scan_k<<<1, 256, 0, stream>>>();
    perm0_k<<<NNODE / 1024, 1024, 0, stream>>>();
    gord1_k<<<NGRP / 1024, 1024, 0, stream>>>();

    // x (B,N) f32 -> WS0 (N,B) bf16
    transpose_bf_k<<<dim3(NNODE / 64, BATCH / 64), dim3(16, 16), 0, stream>>>(x, WS0);

    // sweep 0 (pair 0): WS0 -> WS1 (bf16, full-line NT), LPT node order
    gather_p_k<<<NNODE / 8, 512, 0, stream>>>((const uint4*)WS0, (uint4*)WS1, 0);
    // sweep 1 (pair 1): LDS-staged fused transpose-back, LPT group order
    gather_tr_p_k<<<NGRP, 1024, 0, stream>>>((const uint4*)WS1, OUT, 1);
}

// Round 14
// 488.620 us; speedup vs baseline: 2.4033x; 1.0916x over previous
//
#include <hip/hip_runtime.h>
#include <hip/hip_bf16.h>

#define BATCH 512
#define NNODE 131072
#define NEDGE 131072
#define NLAYER 4
#define SCAN_BLK 1024
#define SCAN_NBLK (NNODE / SCAN_BLK)   // 128
#define PCAP (8 * NEDGE)               // per-pair entry capacity (expected ~4N)

// Per-layer CSR (application order: layer 0 = edges3 ... layer 3 = edges0)
__device__ int g_counts[NLAYER][NNODE];
__device__ int g_offs[NLAYER][NNODE];
__device__ int g_cursor[NLAYER][NNODE];
__device__ int g_srcl[NLAYER][NEDGE];
__device__ int g_bsums[NLAYER][SCAN_NBLK];

// Pair-combined CSR: pair0 = (I+A3)(I+A2), pair1 = (I+A1)(I+A0). Identity included.
__device__ int p_cnt[2][NNODE];
__device__ int p_offs[2][NNODE];
__device__ int p_srcl[2][PCAP];
__device__ int p_bsums[2][SCAN_NBLK];

// Degree-descending permutation per pair (LPT: equal-deg nodes adjacent)
__device__ int s_hist[2][64], s_cur[2][64];
__device__ int d_perm[2][NNODE];

typedef unsigned int uivec4 __attribute__((ext_vector_type(4)));
typedef float fvec4 __attribute__((ext_vector_type(4)));

__device__ __forceinline__ void nt_store_u4(uint4* p, uint4 v) {
    uivec4 w = {v.x, v.y, v.z, v.w};
    __builtin_nontemporal_store(w, reinterpret_cast<uivec4*>(p));
}

__device__ __forceinline__ void nt_store_f4(float* p, float4 v) {
    fvec4 w = {v.x, v.y, v.z, v.w};
    __builtin_nontemporal_store(w, reinterpret_cast<fvec4*>(p));
}

// ---- per-layer CSR build ----
__global__ void zero_counts_k() {
    int i = blockIdx.x * blockDim.x + threadIdx.x;
    ((int*)g_counts)[i] = 0;
}

__global__ void hist_k(const int* __restrict__ p0, const int* __restrict__ p1,
                       const int* __restrict__ p2, const int* __restrict__ p3) {
    int i = blockIdx.x * blockDim.x + threadIdx.x;
    int layer = i >> 17;
    int e = i & (NEDGE - 1);
    const int* eg = layer == 0 ? p0 : layer == 1 ? p1 : layer == 2 ? p2 : p3;
    atomicAdd(&g_counts[layer][eg[NEDGE + e]], 1);
}

__global__ void scan_block_k() {
    __shared__ int sh[SCAN_BLK];
    int layer = blockIdx.x / SCAN_NBLK;
    int blk = blockIdx.x % SCAN_NBLK;
    int t = threadIdx.x;
    int i = blk * SCAN_BLK + t;
    int own = g_counts[layer][i];
    sh[t] = own;
    __syncthreads();
    for (int off = 1; off < SCAN_BLK; off <<= 1) {
        int v = (t >= off) ? sh[t - off] : 0;
        __syncthreads();
        sh[t] += v;
        __syncthreads();
    }
    g_offs[layer][i] = sh[t] - own;
    if (t == SCAN_BLK - 1) g_bsums[layer][blk] = sh[t];
}

__global__ void scan_bsums_k() {
    __shared__ int sh[SCAN_NBLK];
    int layer = blockIdx.x;
    int t = threadIdx.x;
    int own = g_bsums[layer][t];
    sh[t] = own;
    __syncthreads();
    for (int off = 1; off < SCAN_NBLK; off <<= 1) {
        int v = (t >= off) ? sh[t - off] : 0;
        __syncthreads();
        sh[t] += v;
        __syncthreads();
    }
    g_bsums[layer][t] = sh[t] - own;
}

__global__ void scan_add_k() {
    int layer = blockIdx.x / SCAN_NBLK;
    int blk = blockIdx.x % SCAN_NBLK;
    int i = blk * SCAN_BLK + threadIdx.x;
    int o = g_offs[layer][i] + g_bsums[layer][blk];
    g_offs[layer][i] = o;
    g_cursor[layer][i] = o;
}

__global__ void fill_k(const int* __restrict__ p0, const int* __restrict__ p1,
                       const int* __restrict__ p2, const int* __restrict__ p3) {
    int i = blockIdx.x * blockDim.x + threadIdx.x;
    int layer = i >> 17;
    int e = i & (NEDGE - 1);
    const int* eg = layer == 0 ? p0 : layer == 1 ? p1 : layer == 2 ? p2 : p3;
    int s = eg[e];
    int d = eg[NEDGE + e];
    int p = atomicAdd(&g_cursor[layer][d], 1);
    g_srcl[layer][p] = s;
}

// ---- pair combine ----
__global__ void count_pair_k() {
    int i = blockIdx.x * blockDim.x + threadIdx.x;  // 0..2N
    int pr = i >> 17;
    int d = i & (NNODE - 1);
    int U = pr * 2, V = pr * 2 + 1;
    int c = 1 + g_counts[U][d];
    int vb = g_offs[V][d], vd = g_counts[V][d];
    for (int j = 0; j < vd; ++j) {
        int s = g_srcl[V][vb + j];
        c += 1 + g_counts[U][s];
    }
    p_cnt[pr][d] = c;
}

__global__ void pscan_block_k() {
    __shared__ int sh[SCAN_BLK];
    int pr = blockIdx.x / SCAN_NBLK;
    int blk = blockIdx.x % SCAN_NBLK;
    int t = threadIdx.x;
    int i = blk * SCAN_BLK + t;
    int own = p_cnt[pr][i];
    sh[t] = own;
    __syncthreads();
    for (int off = 1; off < SCAN_BLK; off <<= 1) {
        int v = (t >= off) ? sh[t - off] : 0;
        __syncthreads();
        sh[t] += v;
        __syncthreads();
    }
    p_offs[pr][i] = sh[t] - own;
    if (t == SCAN_BLK - 1) p_bsums[pr][blk] = sh[t];
}

__global__ void pscan_bsums_k() {
    __shared__ int sh[SCAN_NBLK];
    int pr = blockIdx.x;
    int t = threadIdx.x;
    int own = p_bsums[pr][t];
    sh[t] = own;
    __syncthreads();
    for (int off = 1; off < SCAN_NBLK; off <<= 1) {
        int v = (t >= off) ? sh[t - off] : 0;
        __syncthreads();
        sh[t] += v;
        __syncthreads();
    }
    p_bsums[pr][t] = sh[t] - own;
}

__global__ void pscan_add_k() {
    int pr = blockIdx.x / SCAN_NBLK;
    int blk = blockIdx.x % SCAN_NBLK;
    int i = blk * SCAN_BLK + threadIdx.x;
    p_offs[pr][i] += p_bsums[pr][blk];
}

__global__ void fill_pair_k() {
    int i = blockIdx.x * blockDim.x + threadIdx.x;  // 0..2N
    int pr = i >> 17;
    int d = i & (NNODE - 1);
    int U = pr * 2, V = pr * 2 + 1;
    int p = p_offs[pr][d];
    int* buf = p_srcl[pr];
    buf[p++] = d;
    int ub = g_offs[U][d], ud = g_counts[U][d];
    for (int j = 0; j < ud; ++j) buf[p++] = g_srcl[U][ub + j];
    int vb = g_offs[V][d], vd = g_counts[V][d];
    for (int j = 0; j < vd; ++j) {
        int s = g_srcl[V][vb + j];
        buf[p++] = s;
        int sb = g_offs[U][s], sd = g_counts[U][s];
        for (int k = 0; k < sd; ++k) buf[p++] = g_srcl[U][sb + k];
    }
}

// ---- degree-descending permutation build (both pairs) ----
__global__ void sort_zero_k() {
    int t = threadIdx.x;   // 128
    ((int*)s_hist)[t] = 0;
}

__global__ void histp_k() {   // 256 blocks x 1024 (128 blocks per pair)
    __shared__ int lh[64];
    int t = threadIdx.x;
    int pr = blockIdx.x >> 7;
    int n = (blockIdx.x & 127) * 1024 + t;
    if (t < 64) lh[t] = 0;
    __syncthreads();
    int b = 63 - min(p_cnt[pr][n], 63);   // descending: heavy first
    atomicAdd(&lh[b], 1);
    __syncthreads();
    if (t < 64) atomicAdd(&s_hist[pr][t], lh[t]);
}

__global__ void sort_scan_k() {   // 1 block, 128 threads: two 64-scans
    __shared__ int sh[2][64];
    int t = threadIdx.x;
    int pr = t >> 6;
    int k = t & 63;
    sh[pr][k] = s_hist[pr][k];
    __syncthreads();
    for (int off = 1; off < 64; off <<= 1) {
        int v = (k >= off) ? sh[pr][k - off] : 0;
        __syncthreads();
        sh[pr][k] += v;
        __syncthreads();
    }
    s_cur[pr][k] = sh[pr][k] - s_hist[pr][k];   // exclusive
}

__global__ void permp_k() {   // 256 blocks x 1024
    __shared__ int lh[64];
    __shared__ int lbase[64];
    int t = threadIdx.x;
    int pr = blockIdx.x >> 7;
    int n = (blockIdx.x & 127) * 1024 + t;
    if (t < 64) lh[t] = 0;
    __syncthreads();
    int b = 63 - min(p_cnt[pr][n], 63);
    int lpos = atomicAdd(&lh[b], 1);
    __syncthreads();
    if (t < 64) lbase[t] = lh[t] ? atomicAdd(&s_cur[pr][t], lh[t]) : 0;
    __syncthreads();
    d_perm[pr][lbase[b] + lpos] = n;
}

// ---- transpose in: x (B,N) f32 -> out (N,B) bf16. 64x64 tiles, (16,16) ----
__global__ void transpose_bf_k(const float* __restrict__ in, unsigned short* __restrict__ out) {
    __shared__ float tile[64][65];
    int c0 = blockIdx.x * 64;   // N dim
    int r0 = blockIdx.y * 64;   // B dim
    int tx = threadIdx.x;
    int ty = threadIdx.y;
    float4 v[4];
#pragma unroll
    for (int i = 0; i < 4; ++i)
        v[i] = *reinterpret_cast<const float4*>(&in[(size_t)(r0 + ty + 16 * i) * NNODE + c0 + 4 * tx]);
#pragma unroll
    for (int i = 0; i < 4; ++i) {
        tile[ty + 16 * i][4 * tx + 0] = v[i].x;
        tile[ty + 16 * i][4 * tx + 1] = v[i].y;
        tile[ty + 16 * i][4 * tx + 2] = v[i].z;
        tile[ty + 16 * i][4 * tx + 3] = v[i].w;
    }
    __syncthreads();
#pragma unroll
    for (int i = 0; i < 4; ++i) {
        int n = c0 + ty + 16 * i;
        ushort4 w;
        __hip_bfloat16 h0 = __float2bfloat16(tile[4 * tx + 0][ty + 16 * i]);
        __hip_bfloat16 h1 = __float2bfloat16(tile[4 * tx + 1][ty + 16 * i]);
        __hip_bfloat16 h2 = __float2bfloat16(tile[4 * tx + 2][ty + 16 * i]);
        __hip_bfloat16 h3 = __float2bfloat16(tile[4 * tx + 3][ty + 16 * i]);
        w.x = *reinterpret_cast<unsigned short*>(&h0);
        w.y = *reinterpret_cast<unsigned short*>(&h1);
        w.z = *reinterpret_cast<unsigned short*>(&h2);
        w.w = *reinterpret_cast<unsigned short*>(&h3);
        *reinterpret_cast<ushort4*>(&out[(size_t)n * BATCH + r0 + 4 * tx]) = w;
    }
}

// ---- transpose out: in (N,B) bf16 -> out (B,N) f32. 64x64 tiles, (16,16) ----
__global__ void transpose_fb_k(const unsigned short* __restrict__ in, float* __restrict__ out) {
    __shared__ float tile[64][65];    // [n-local][b-local]
    int n0 = blockIdx.x * 64;
    int b0 = blockIdx.y * 64;
    int tx = threadIdx.x;
    int ty = threadIdx.y;
#pragma unroll
    for (int i = 0; i < 4; ++i) {
        int nl = ty + 16 * i;
        ushort4 w = *reinterpret_cast<const ushort4*>(&in[(size_t)(n0 + nl) * BATCH + b0 + 4 * tx]);
        tile[nl][4 * tx + 0] = __uint_as_float((unsigned)w.x << 16);
        tile[nl][4 * tx + 1] = __uint_as_float((unsigned)w.y << 16);
        tile[nl][4 * tx + 2] = __uint_as_float((unsigned)w.z << 16);
        tile[nl][4 * tx + 3] = __uint_as_float((unsigned)w.w << 16);
    }
    __syncthreads();
#pragma unroll
    for (int i = 0; i < 4; ++i) {
        int bl = ty + 16 * i;
        float4 w;
        w.x = tile[4 * tx + 0][bl];
        w.y = tile[4 * tx + 1][bl];
        w.z = tile[4 * tx + 2][bl];
        w.w = tile[4 * tx + 3][bl];
        nt_store_f4(&out[(size_t)(b0 + bl) * NNODE + n0 + 4 * tx], w);
    }
}

// bf16 unpack-accumulate: uint4 = 8 bf16 -> 8 f32 adds
__device__ __forceinline__ void gacc8(float* a, uint4 v) {
    a[0] += __uint_as_float(v.x << 16);
    a[1] += __uint_as_float(v.x & 0xffff0000u);
    a[2] += __uint_as_float(v.y << 16);
    a[3] += __uint_as_float(v.y & 0xffff0000u);
    a[4] += __uint_as_float(v.z << 16);
    a[5] += __uint_as_float(v.z & 0xffff0000u);
    a[6] += __uint_as_float(v.w << 16);
    a[7] += __uint_as_float(v.w & 0xffff0000u);
}

__device__ __forceinline__ unsigned pack2(float lo, float hi) {
    __hip_bfloat16 l = __float2bfloat16(lo);
    __hip_bfloat16 h = __float2bfloat16(hi);
    return (unsigned)*reinterpret_cast<unsigned short*>(&l) |
           ((unsigned)*reinterpret_cast<unsigned short*>(&h) << 16);
}

// ---- MLP gather: each wave owns 4 LPT-adjacent nodes (similar degs).
// Inner loop: 2 rounds x 4 nodes = up to 8 independent 1KB wave-loads in flight
// before any accumulate. 512 threads = 8 waves -> 32 nodes per block.
__global__ void __launch_bounds__(512) gather4_k(const uint4* __restrict__ cur,
                                                 uint4* __restrict__ out, int pr) {
    int t = threadIdx.x;
    int q = t & 63;
    int wv = t >> 6;                        // 0..7
    int base = blockIdx.x * 32 + wv * 4;
    int n[4], deg[4];
    const int* sl[4];
#pragma unroll
    for (int k = 0; k < 4; ++k) {
        n[k] = d_perm[pr][base + k];
        deg[k] = __builtin_amdgcn_readfirstlane(p_cnt[pr][n[k]]);
        sl[k] = &p_srcl[pr][p_offs[pr][n[k]]];
    }
    float acc[4][8];
#pragma unroll
    for (int k = 0; k < 4; ++k)
#pragma unroll
        for (int m = 0; m < 8; ++m) acc[k][m] = 0.f;
    int jmax = max(max(deg[0], deg[1]), max(deg[2], deg[3]));
    int j = 0;
    for (; j + 2 <= jmax; j += 2) {
        uint4 v[8];
#pragma unroll
        for (int k = 0; k < 4; ++k) {
            if (j < deg[k])     v[2 * k]     = cur[(size_t)sl[k][j] * 64 + q];
            if (j + 1 < deg[k]) v[2 * k + 1] = cur[(size_t)sl[k][j + 1] * 64 + q];
        }
#pragma unroll
        for (int k = 0; k < 4; ++k) {
            if (j < deg[k])     gacc8(acc[k], v[2 * k]);
            if (j + 1 < deg[k]) gacc8(acc[k], v[2 * k + 1]);
        }
    }
    if (j < jmax) {
        uint4 v[4];
#pragma unroll
        for (int k = 0; k < 4; ++k)
            if (j < deg[k]) v[k] = cur[(size_t)sl[k][j] * 64 + q];
#pragma unroll
        for (int k = 0; k < 4; ++k)
            if (j < deg[k]) gacc8(acc[k], v[k]);
    }
#pragma unroll
    for (int k = 0; k < 4; ++k) {
        uint4 w;
        w.x = pack2(acc[k][0], acc[k][1]);
        w.y = pack2(acc[k][2], acc[k][3]);
        w.z = pack2(acc[k][4], acc[k][5]);
        w.w = pack2(acc[k][6], acc[k][7]);
        nt_store_u4(&out[(size_t)n[k] * 64 + q], w);
    }
}

extern "C" void kernel_launch(void* const* d_in, const int* in_sizes, int n_in,
                              void* d_out, int out_size, void* d_ws, size_t ws_size,
                              hipStream_t stream) {
    const float* x = (const float*)d_in[0];
    // Application order: edges3 (layer 0) ... edges0 (layer 3)
    const int* p0 = (const int*)d_in[4];
    const int* p1 = (const int*)d_in[3];
    const int* p2 = (const int*)d_in[2];
    const int* p3 = (const int*)d_in[1];

    // Two bf16 (N,B) buffers in d_ws: 128 MB each
    unsigned short* WS0 = (unsigned short*)d_ws;
    unsigned short* WS1 = WS0 + (size_t)NNODE * BATCH;
    float* OUT = (float*)d_out;

    // Per-layer CSR
    zero_counts_k<<<NLAYER * NNODE / 1024, 1024, 0, stream>>>();
    hist_k<<<NLAYER * NEDGE / 1024, 1024, 0, stream>>>(p0, p1, p2, p3);
    scan_block_k<<<NLAYER * SCAN_NBLK, SCAN_BLK, 0, stream>>>();
    scan_bsums_k<<<NLAYER, SCAN_NBLK, 0, stream>>>();
    scan_add_k<<<NLAYER * SCAN_NBLK, SCAN_BLK, 0, stream>>>();
    fill_k<<<NLAYER * NEDGE / 1024, 1024, 0, stream>>>(p0, p1, p2, p3);

    // Pair-combined CSR (2 pairs)
    count_pair_k<<<2 * NNODE / 1024, 1024, 0, stream>>>();
    pscan_block_k<<<2 * SCAN_NBLK, SCAN_BLK, 0, stream>>>();
    pscan_bsums_k<<<2, SCAN_NBLK, 0, stream>>>();
    pscan_add_k<<<2 * SCAN_NBLK, SCAN_BLK, 0, stream>>>();
    fill_pair_k<<<2 * NNODE / 256, 256, 0, stream>>>();

    // Degree-descending permutations for both pairs
    sort_zero_k<<<1, 128, 0, stream>>>();
    histp_k<<<2 * NNODE / 1024, 1024, 0, stream>>>();
    sort_scan_k<<<1, 128, 0, stream>>>();
    permp_k<<<2 * NNODE / 1024, 1024, 0, stream>>>();

    // x (B,N) f32 -> WS0 (N,B) bf16
    transpose_bf_k<<<dim3(NNODE / 64, BATCH / 64), dim3(16, 16), 0, stream>>>(x, WS0);

    // sweep 0 (pair 0): WS0 -> WS1 (bf16, full-line NT)
    gather4_k<<<NNODE / 32, 512, 0, stream>>>((const uint4*)WS0, (uint4*)WS1, 0);
    // sweep 1 (pair 1): WS1 -> WS0 (bf16, full-line NT)
    gather4_k<<<NNODE / 32, 512, 0, stream>>>((const uint4*)WS1, (uint4*)WS0, 1);
    // transpose back: WS0 (N,B) bf16 -> d_out (B,N) f32 (full-line NT)
    transpose_fb_k<<<dim3(NNODE / 64, BATCH / 64), dim3(16, 16), 0, stream>>>(WS0, OUT);
}